// Round 10
// baseline (171.894 us; speedup 1.0000x reference)
//
#include <hip/hip_runtime.h>

// LoopHead: node MLP (32->64->32) then edge decoder (gather/concat -> 64 -> 1)
// Counter-verified: R10 TLP neutral; R12 VALU-shave neutral (67us, BEST);
// R13 LDS pipe regressed; R14 int8+row-scales 96us; R16 int8+LDS-scales 86us;
// R17 i8-MFMA+masked-pair+scale-gathers 90us (absmax 0.03125 -> weight quant
// proven safe). Real (de-inflated /4) VALUBusy 12-18%, MfmaUtil 3-4% in all
// variants -> ~80% of cycles issue nothing; fixed non-edge overhead ~80us.
// Empirical law: every instruction class added to the R12 loop made it
// slower; scale MACHINERY (not int8 data) killed R14-R17.
// R19: int8 + ONE GLOBAL SCALE -> edge loop strictly leaner than R12:
//   2 divergent 16B gathers (vs 4x8B), 8 MFMA i32_16x16x64_i8 (vs 16 bf16;
//   zi||zj in one K=64 call since scales match), ~150 VALU, zero scale
//   loads/shuffles (S=gz*wsc folded into bias'/w2' per-thread consts).
// Plumbing: node writes bf16 z to D_OUT-AS-SCRATCH (overwritten by edge
// later) + per-tile atomicMax(gmax); tiny quant kernel -> z8 (3.2MB ws).
// Accuracy gamble (pre-committed): global step ~2x group-4 step ->
// absmax ~0.04-0.06; on fail revert to group-4 scales.

typedef short bfrag4 __attribute__((ext_vector_type(4)));  // 4 bf16 (x16 frag)
typedef float f32x4v __attribute__((ext_vector_type(4)));  // fp32 x4
typedef int   i32x4  __attribute__((ext_vector_type(4)));  // int32 x4 (16B)

#define N_NODES 100000
#define N_EDGES 3200000

__device__ __forceinline__ unsigned short f2bf(float f) {
    unsigned int i = __float_as_uint(f);
    unsigned int r = i + 0x7FFFu + ((i >> 16) & 1u);  // RNE
    return (unsigned short)(r >> 16);
}

__device__ __forceinline__ float bf2f(unsigned short b) {
    unsigned int u = ((unsigned int)b) << 16;
    return __uint_as_float(u);
}

__device__ __forceinline__ bfrag4 cvt4(float x0, float x1, float x2, float x3) {
    bfrag4 v;
    v[0] = (short)f2bf(x0);
    v[1] = (short)f2bf(x1);
    v[2] = (short)f2bf(x2);
    v[3] = (short)f2bf(x3);
    return v;
}

// ---------------- Kernel 1: node projection -> z16 (bf16) + global max -----
// MFMA pipeline is the harness-proven R9 version; epilogue adds a per-tile
// atomicMax of |z| into gmax (uint-ordered float, all values >= 0).
__global__ __launch_bounds__(256) void node_proj_kernel(
    const float* __restrict__ z_mod,   // [N,32] fp32
    const float* __restrict__ w1,      // [32,64] row-major (k,n)
    const float* __restrict__ b1,      // [64]
    const float* __restrict__ w2,      // [64,32] row-major (k,n)
    const float* __restrict__ b2,      // [32]
    unsigned short* __restrict__ z16,  // [N,32] bf16 out (d_out scratch)
    unsigned int*   __restrict__ gmax) // [1] global |z| max (float bits)
{
    __shared__ unsigned short hbuf[4][16 * 72];

    const int tid  = threadIdx.x;
    const int wave = tid >> 6;
    const int lane = tid & 63;
    const int quad = lane >> 4;
    const int col  = lane & 15;

    bfrag4 bw1[2][4];   // stage 1: K=32 (2 steps), N=64 (4 n-tiles)
    float  bias1[4];
    for (int t = 0; t < 4; ++t) {
        const int n = col + 16 * t;
        for (int s = 0; s < 2; ++s)
            for (int j = 0; j < 4; ++j)
                bw1[s][t][j] = (short)f2bf(w1[(s * 16 + quad * 4 + j) * 64 + n]);
        bias1[t] = b1[n];
    }
    bfrag4 bw2[4][2];   // stage 2: K=64 (4 steps), N=32 (2 n-tiles)
    float  bias2[2];
    for (int t = 0; t < 2; ++t) {
        const int n = col + 16 * t;
        for (int s = 0; s < 4; ++s)
            for (int j = 0; j < 4; ++j)
                bw2[s][t][j] = (short)f2bf(w2[(s * 16 + quad * 4 + j) * 32 + n]);
        bias2[t] = b2[n];
    }

    unsigned short* hrow = &hbuf[wave][0];

    const int gwave  = blockIdx.x * 4 + wave;
    const int nwaves = gridDim.x * 4;
    const int ntiles = N_NODES / 16;   // 6250, exact

    float wmax = 0.f;   // per-thread running tile max

    for (int tile = gwave; tile < ntiles; tile += nwaves) {
        const int node0 = tile * 16;
        const float* zrow = z_mod + (size_t)(node0 + col) * 32;

        f32x4v za0 = *(const f32x4v*)(zrow + 0 * 16 + quad * 4);
        f32x4v za1 = *(const f32x4v*)(zrow + 1 * 16 + quad * 4);
        bfrag4 a10 = cvt4(za0[0], za0[1], za0[2], za0[3]);
        bfrag4 a11 = cvt4(za1[0], za1[1], za1[2], za1[3]);

        f32x4v acc[4];
        for (int t = 0; t < 4; ++t) {
            f32x4v c = {bias1[t], bias1[t], bias1[t], bias1[t]};
            c = __builtin_amdgcn_mfma_f32_16x16x16bf16_1k(a10, bw1[0][t], c, 0, 0, 0);
            c = __builtin_amdgcn_mfma_f32_16x16x16bf16_1k(a11, bw1[1][t], c, 0, 0, 0);
            acc[t] = c;
        }

        for (int t = 0; t < 4; ++t)
            for (int r = 0; r < 4; ++r) {
                float v = acc[t][r];
                v = v > 0.f ? v : 0.f;
                hrow[(quad * 4 + r) * 72 + (col + 16 * t)] = f2bf(v);
            }
        asm volatile("" ::: "memory");

        f32x4v acc2[2];
        for (int t = 0; t < 2; ++t)
            acc2[t] = (f32x4v){bias2[t], bias2[t], bias2[t], bias2[t]};
        for (int s = 0; s < 4; ++s) {
            bfrag4 a2 = *(const bfrag4*)(hrow + col * 72 + s * 16 + quad * 4);
            for (int t = 0; t < 2; ++t)
                acc2[t] = __builtin_amdgcn_mfma_f32_16x16x16bf16_1k(a2, bw2[s][t], acc2[t], 0, 0, 0);
        }
        asm volatile("" ::: "memory");

        // bf16 z store (R9-proven path) + track |z| max
        for (int t = 0; t < 2; ++t)
            for (int r = 0; r < 4; ++r) {
                float v = acc2[t][r];
                wmax = fmaxf(wmax, fabsf(v));
                z16[(size_t)(node0 + quad * 4 + r) * 32 + (col + 16 * t)] =
                    f2bf(v);
            }
    }

    // one atomic per wave
    for (int mask = 1; mask <= 32; mask <<= 1)
        wmax = fmaxf(wmax, __shfl_xor(wmax, mask, 64));
    if (lane == 0)
        atomicMax(gmax, __float_as_uint(wmax));
}

// ---------------- Kernel 1b: quantize z16 -> z8 with global scale ----------
__global__ __launch_bounds__(256) void quant8_kernel(
    const unsigned short* __restrict__ z16,   // [N,32] bf16
    const unsigned int*   __restrict__ gmax,  // [1]
    char* __restrict__ z8)                    // [N,32] int8
{
    const int idx = blockIdx.x * 256 + threadIdx.x;   // 8 elems/thread
    if (idx >= N_NODES * 32 / 8) return;
    const float M   = __uint_as_float(*gmax);
    const float inv = 127.f / fmaxf(M, 1e-30f);

    i32x4 v = *(const i32x4*)(z16 + (size_t)idx * 8);   // 8 bf16
    unsigned long long pk = 0;
#pragma unroll
    for (int i = 0; i < 4; ++i) {
        unsigned int w = (unsigned int)v[i];
        int q0 = (int)rintf(bf2f((unsigned short)(w & 0xFFFF)) * inv);
        int q1 = (int)rintf(bf2f((unsigned short)(w >> 16)) * inv);
        pk |= ((unsigned long long)(q0 & 0xFF)) << (16 * i);
        pk |= ((unsigned long long)(q1 & 0xFF)) << (16 * i + 8);
    }
    *(unsigned long long*)(z8 + (size_t)idx * 8) = pk;
}

// ---------------- Kernel 2: edge decoder (R19: i8 MFMA, global scale) ------
__global__ __launch_bounds__(256) void edge_dec_kernel(
    const int*          __restrict__ eidx,   // [2, E] int32
    const char*         __restrict__ z8,     // [N,32] int8
    const unsigned int* __restrict__ gmax,   // [1]
    const float*        __restrict__ dw1,    // [64,64] row-major (k,n)
    const float*        __restrict__ db1,    // [64]
    const float*        __restrict__ dw2,    // [64]
    const float*        __restrict__ db2,    // [1]
    float* __restrict__ out)                 // [E] fp32
{
    const int tid  = threadIdx.x;
    const int lane = tid & 63;
    const int quad = lane >> 4;
    const int col  = lane & 15;
    const int ss   = quad >> 1;   // 0 = src row (zi: k<32), 1 = dst (zj)
    const int hf   = quad & 1;    // which 16B half of the 32B int8 row

    const float gz = __uint_as_float(*gmax) * (1.f / 127.f);

    // ---- preamble: int8-quantize dw1^T per output row m (R17-proven) ------
    // A-frag (i8 16x16x64): lane(col,quad) holds A[m=16mt+col][k=quad*16+j]
    i32x4 awq[4];
    float wscv[4];
    for (int mt = 0; mt < 4; ++mt) {
        const int m = 16 * mt + col;
        float w[16];
        float mx = 0.f;
        for (int j = 0; j < 16; ++j) {
            w[j] = dw1[(quad * 16 + j) * 64 + m];
            mx = fmaxf(mx, fabsf(w[j]));
        }
        mx = fmaxf(mx, __shfl_xor(mx, 16, 64));
        mx = fmaxf(mx, __shfl_xor(mx, 32, 64));
        wscv[mt] = mx * (1.f / 127.f);
        const float winv = 127.f / fmaxf(mx, 1e-30f);
        i32x4 a;
        for (int rr = 0; rr < 4; ++rr) {
            int pk = 0;
            for (int bi = 0; bi < 4; ++bi) {
                int q = (int)rintf(w[rr * 4 + bi] * winv);
                pk |= (q & 0xFF) << (8 * bi);
            }
            a[rr] = pk;
        }
        awq[mt] = a;
    }
    // epilogue consts at m = 16mt + quad*4 + r (C-layout):
    //   h = S*(acc + b/S), p += relu-part * (S*w2); store bS = b/S, wS = S*w2
    float bS[4][4], wS[4][4];
    for (int mt = 0; mt < 4; ++mt)
        for (int r = 0; r < 4; ++r) {
            const float S = __shfl(wscv[mt], quad * 4 + r, 64) * gz;  // > 0
            bS[mt][r] = db1[16 * mt + quad * 4 + r] / S;
            wS[mt][r] = dw2[16 * mt + quad * 4 + r] * S;
        }
    const float bias2 = db2[0];

    const int gwave  = blockIdx.x * 4 + (tid >> 6);
    const int nwaves = gridDim.x * 4;     // 8192
    const int npairs = N_EDGES / 32;      // 100000, exact

    const int iofs = ss * N_EDGES + col;  // this lane's index column

    int iA = eidx[gwave * 32 + iofs];
    int iB = eidx[gwave * 32 + 16 + iofs];

    for (int p = gwave; p < npairs; p += nwaves) {
        const int e0 = p * 32;

        // 2 divergent 16B gathers/iter — the bytes ARE the full K=64 i8
        // B-frag (zi||zj; same scale -> ONE mfma per m-tile).
        i32x4 gA = *(const i32x4*)(z8 + (size_t)iA * 32 + hf * 16);
        i32x4 gB = *(const i32x4*)(z8 + (size_t)iB * 32 + hf * 16);

        // prefetch NEXT iteration's indices (branchless clamp — always valid)
        const int pn = p + nwaves;
        const int pc = pn < npairs ? pn : gwave;
        iA = eidx[pc * 32 + iofs];
        iB = eidx[pc * 32 + 16 + iofs];

        const i32x4 zc = {0, 0, 0, 0};
        i32x4 aA[4], aB[4];
        for (int mt = 0; mt < 4; ++mt) {
            aA[mt] = __builtin_amdgcn_mfma_i32_16x16x64_i8(awq[mt], gA, zc, 0, 0, 0);
            aB[mt] = __builtin_amdgcn_mfma_i32_16x16x64_i8(awq[mt], gB, zc, 0, 0, 0);
        }

        // epilogue: h' = acc + b/S; relu; p += h' * (S*w2)
        float pA = 0.f, pB = 0.f;
        for (int mt = 0; mt < 4; ++mt)
            for (int r = 0; r < 4; ++r) {
                float hA = (float)aA[mt][r] + bS[mt][r];
                float hB = (float)aB[mt][r] + bS[mt][r];
                hA = hA > 0.f ? hA : 0.f;
                hB = hB > 0.f ? hB : 0.f;
                pA = fmaf(hA, wS[mt][r], pA);
                pB = fmaf(hB, wS[mt][r], pB);
            }
        pA += __shfl_xor(pA, 16, 64);
        pA += __shfl_xor(pA, 32, 64);
        pB += __shfl_xor(pB, 16, 64);
        pB += __shfl_xor(pB, 32, 64);

        if (lane < 32) {
            float v = (lane < 16 ? pA : pB) + bias2;
            out[e0 + lane] = v;
        }
    }
}

extern "C" void kernel_launch(void* const* d_in, const int* in_sizes, int n_in,
                              void* d_out, int out_size, void* d_ws, size_t ws_size,
                              hipStream_t stream) {
    const float* z_mod = (const float*)d_in[0];
    const int*   eidx  = (const int*)d_in[1];
    const float* w1    = (const float*)d_in[2];
    const float* b1    = (const float*)d_in[3];
    const float* w2    = (const float*)d_in[4];
    const float* b2    = (const float*)d_in[5];
    const float* dw1   = (const float*)d_in[6];
    const float* db1   = (const float*)d_in[7];
    const float* dw2   = (const float*)d_in[8];
    const float* db2   = (const float*)d_in[9];
    float* out = (float*)d_out;

    char*         z8   = (char*)d_ws;                                 // 3.2 MB
    unsigned int* gmax = (unsigned int*)((char*)d_ws + (size_t)N_NODES * 32);
    // z16 scratch lives in d_out (6.4 MB of 12.8 MB; fully overwritten by
    // the edge kernel afterwards)
    unsigned short* z16 = (unsigned short*)d_out;

    hipMemsetAsync(gmax, 0, 4, stream);
    node_proj_kernel<<<512, 256, 0, stream>>>(z_mod, w1, b1, w2, b2, z16, gmax);
    quant8_kernel<<<1563, 256, 0, stream>>>(z16, gmax, z8);
    edge_dec_kernel<<<2048, 256, 0, stream>>>(eidx, z8, gmax, dw1, db1, dw2, db2, out);
}